// Round 2
// baseline (547.996 us; speedup 1.0000x reference)
//
#include <hip/hip_runtime.h>

// Problem constants (from reference)
#define BB 16
#define SS 4096
#define HH 1024
#define NW 2048      // N (max word tokens)
#define DWW 50       // glove dim
#define OUTW (HH + DWW)   // 1074
#define CHUNKS 32
#define CHUNK 64     // CHUNKS*CHUNK = 2048 >= max(ns-1) = 2047

// ws layout (bytes):
//   start  : BB*(NW+1) ints              = 131,136 B   (offset 0)
//   partial: BB*CHUNKS*HH floats         = 2,097,152 B (offset 131,136; 16B aligned)
//   last_w : BB*64 floats                = 4,096 B
#define WS_START_OFF   0
#define WS_PARTIAL_OFF (BB * (NW + 1) * 4)
#define WS_LASTW_OFF   (WS_PARTIAL_OFF + BB * CHUNKS * HH * 4)

__global__ __launch_bounds__(256) void k_prep(
    const float* __restrict__ wemb, const int* __restrict__ seg,
    const int* __restrict__ ns, int* __restrict__ start,
    float* __restrict__ lastw) {
  const int b = blockIdx.x;
  const int t = threadIdx.x;

  // init span starts to S (sentinel end)
  int* sb = start + b * (NW + 1);
  for (int w = t; w <= NW; w += 256) sb[w] = SS;
  __syncthreads();

  // scatter: first subword of each word (seg_ids sorted, contiguous spans)
  const int* segb = seg + b * SS;
  for (int s = t; s < SS; s += 256) {
    int v = segb[s];
    if (s == 0 || segb[s - 1] != v) sb[v] = s;
  }

  // last_w[b, d] = max over w < ns of word_emb[b, w, d]
  const int nsb = ns[b];
  const int d = t & 63;
  const int r = t >> 6;  // 0..3
  float m = -INFINITY;
  if (d < DWW) {
    const float* wb = wemb + (size_t)b * NW * DWW;
    for (int w = r; w < nsb; w += 4) m = fmaxf(m, wb[(size_t)w * DWW + d]);
  }
  __shared__ float red[256];
  red[t] = m;
  __syncthreads();
  if (r == 0 && d < DWW) {
    float mm = fmaxf(fmaxf(red[d], red[64 + d]), fmaxf(red[128 + d], red[192 + d]));
    lastw[b * 64 + d] = mm;
  }
}

__global__ __launch_bounds__(256) void k_prefix(
    const float* __restrict__ ctx, const int* __restrict__ ns,
    float* __restrict__ partial) {
  const int c = blockIdx.x;   // chunk
  const int b = blockIdx.y;   // batch
  const int t = threadIdx.x;
  const int lim = ns[b] - 1;  // subwords [0, lim) feed last_ctx
  const int s0 = c * CHUNK;
  const int s1 = min(s0 + CHUNK, lim);

  float4 m = make_float4(-INFINITY, -INFINITY, -INFINITY, -INFINITY);
  const float* cb = ctx + (size_t)b * SS * HH;
  for (int s = s0; s < s1; ++s) {
    const float4 v = *reinterpret_cast<const float4*>(cb + (size_t)s * HH + 4 * t);
    m.x = fmaxf(m.x, v.x);
    m.y = fmaxf(m.y, v.y);
    m.z = fmaxf(m.z, v.z);
    m.w = fmaxf(m.w, v.w);
  }
  float4* p = reinterpret_cast<float4*>(partial + ((size_t)b * CHUNKS + c) * HH);
  p[t] = m;
}

__global__ __launch_bounds__(256) void k_main(
    const float* __restrict__ ctx, const float* __restrict__ wemb,
    const int* __restrict__ ns, const int* __restrict__ start,
    const float* __restrict__ partial, const float* __restrict__ lastw,
    float* __restrict__ out) {
  const int w = blockIdx.x;
  const int b = blockIdx.y;
  const int t = threadIdx.x;
  const int nsb = ns[b];
  float* orow = out + ((size_t)b * NW + w) * OUTW;

  if (w >= nsb) {  // padding word positions -> zero vector
    // 1074 floats = 537 float2 (rows are 8B aligned)
    float2* o2 = reinterpret_cast<float2*>(orow);
    for (int j = t; j < OUTW / 2; j += 256) o2[j] = make_float2(0.0f, 0.0f);
    if (t == 0) orow[OUTW - 1] = 0.0f;  // odd tail element (537*2 = 1074, none) -- keep safe
    return;
  }

  float4 m = make_float4(-INFINITY, -INFINITY, -INFINITY, -INFINITY);
  if (w == nsb - 1) {
    // last word token: reduce the 32 chunk partials (prefix max of context)
    const float* p = partial + (size_t)b * CHUNKS * HH;
    for (int c = 0; c < CHUNKS; ++c) {
      const float4 v = *reinterpret_cast<const float4*>(p + (size_t)c * HH + 4 * t);
      m.x = fmaxf(m.x, v.x);
      m.y = fmaxf(m.y, v.y);
      m.z = fmaxf(m.z, v.z);
      m.w = fmaxf(m.w, v.w);
    }
  } else {
    // segment max over this word's contiguous subword span
    const int s0 = start[b * (NW + 1) + w];
    const int s1 = start[b * (NW + 1) + w + 1];
    const float* cb = ctx + (size_t)b * SS * HH;
    for (int s = s0; s < s1; ++s) {
      const float4 v = *reinterpret_cast<const float4*>(cb + (size_t)s * HH + 4 * t);
      m.x = fmaxf(m.x, v.x);
      m.y = fmaxf(m.y, v.y);
      m.z = fmaxf(m.z, v.z);
      m.w = fmaxf(m.w, v.w);
    }
  }

  // Store H part. Row stride is 1074 floats -> rows only 8B aligned; use float2.
  float2* o2 = reinterpret_cast<float2*>(orow);
  o2[2 * t]     = make_float2(m.x, m.y);
  o2[2 * t + 1] = make_float2(m.z, m.w);

  // DW tail
  if (t < DWW) {
    float v;
    if (w == nsb - 1) v = lastw[b * 64 + t];
    else              v = wemb[((size_t)b * NW + w) * DWW + t];
    orow[HH + t] = v;
  }
}

extern "C" void kernel_launch(void* const* d_in, const int* in_sizes, int n_in,
                              void* d_out, int out_size, void* d_ws, size_t ws_size,
                              hipStream_t stream) {
  const float* ctx  = (const float*)d_in[0];  // [B,S,H]
  const float* wemb = (const float*)d_in[1];  // [B,N,DW]
  const int*   seg  = (const int*)d_in[2];    // [B,S]
  const int*   ns   = (const int*)d_in[3];    // [B]
  float* out = (float*)d_out;

  char* ws = (char*)d_ws;
  int*   start   = (int*)(ws + WS_START_OFF);
  float* partial = (float*)(ws + WS_PARTIAL_OFF);
  float* lastw   = (float*)(ws + WS_LASTW_OFF);

  k_prep<<<dim3(BB), dim3(256), 0, stream>>>(wemb, seg, ns, start, lastw);
  k_prefix<<<dim3(CHUNKS, BB), dim3(256), 0, stream>>>(ctx, ns, partial);
  k_main<<<dim3(NW, BB), dim3(256), 0, stream>>>(ctx, wemb, ns, start, partial, lastw, out);
}

// Round 3
// 436.625 us; speedup vs baseline: 1.2551x; 1.2551x over previous
//
#include <hip/hip_runtime.h>

// Problem constants (from reference)
#define BB 16
#define SS 4096
#define HH 1024
#define NW 2048      // N (max word tokens)
#define DWW 50       // glove dim
#define OUTW (HH + DWW)   // 1074
#define CHUNKS 32
#define CHUNK 64          // CHUNKS*CHUNK = 2048 >= max(ns-1) = 2047
#define SEGSLICE (SS / CHUNKS)   // 128 subwords per block for the scatter

// ws layout (bytes):
//   start    : BB*NW ints          = 131,072 B  (offset 0)
//   partial  : BB*CHUNKS*HH floats = 2,097,152 B
//   lastw_p  : BB*CHUNKS*64 floats = 131,072 B
#define WS_START_OFF   0
#define WS_PARTIAL_OFF (BB * NW * 4)
#define WS_LASTWP_OFF  (WS_PARTIAL_OFF + BB * CHUNKS * HH * 4)

// One fused prep kernel, grid (CHUNKS, B) = 512 blocks:
//  1) scatter span starts for its 128-subword slice (no init needed)
//  2) partial last_w over its 64-word slice of word_emb
//  3) partial prefix-max of context rows [c*64, c*64+64) ∩ [0, ns-1)
__global__ __launch_bounds__(256) void k_pre(
    const float* __restrict__ ctx, const float* __restrict__ wemb,
    const int* __restrict__ seg, const int* __restrict__ ns,
    int* __restrict__ start, float* __restrict__ partial,
    float* __restrict__ lastwp) {
  const int c = blockIdx.x;
  const int b = blockIdx.y;
  const int t = threadIdx.x;
  const int nsb = ns[b];

  // --- 1) span-start scatter (each word's first subword). seg is sorted. ---
  const int* segb = seg + b * SS;
  int* sb = start + b * NW;
  const int sbase = c * SEGSLICE;
  if (t < SEGSLICE) {
    const int s = sbase + t;
    const int v = segb[s];
    if (s == 0 || segb[s - 1] != v) sb[v] = s;
  }

  // --- 2) last_w partial over words [c*64, c*64+64) ∩ [0, nsb) ---
  {
    const int d = t & 63;        // dim (valid < 50)
    const int r = t >> 6;        // 0..3 (4 words in parallel)
    float m = -INFINITY;
    if (d < DWW) {
      const float* wb = wemb + (size_t)b * NW * DWW;
      for (int i = 0; i < CHUNK / 4; ++i) {
        const int w = c * CHUNK + 4 * i + r;
        if (w < nsb) m = fmaxf(m, wb[(size_t)w * DWW + d]);
      }
    }
    __shared__ float red[256];
    red[t] = m;
    __syncthreads();
    if (r == 0 && d < DWW) {
      lastwp[((size_t)b * CHUNKS + c) * 64 + d] =
          fmaxf(fmaxf(red[d], red[64 + d]), fmaxf(red[128 + d], red[192 + d]));
    }
  }

  // --- 3) ctx prefix partial: rows [c*64, c*64+64) ∩ [0, nsb-1) ---
  {
    const int lim = nsb - 1;
    const int s0 = c * CHUNK;
    const int s1 = min(s0 + CHUNK, lim);
    float4 m = make_float4(-INFINITY, -INFINITY, -INFINITY, -INFINITY);
    const float* cb = ctx + (size_t)b * SS * HH;
    for (int s = s0; s < s1; ++s) {
      const float4 v = *reinterpret_cast<const float4*>(cb + (size_t)s * HH + 4 * t);
      m.x = fmaxf(m.x, v.x);
      m.y = fmaxf(m.y, v.y);
      m.z = fmaxf(m.z, v.z);
      m.w = fmaxf(m.w, v.w);
    }
    float4* p = reinterpret_cast<float4*>(partial + ((size_t)b * CHUNKS + c) * HH);
    p[t] = m;
  }
}

__global__ __launch_bounds__(256) void k_main(
    const float* __restrict__ ctx, const float* __restrict__ wemb,
    const int* __restrict__ ns, const int* __restrict__ start,
    const float* __restrict__ partial, const float* __restrict__ lastwp,
    float* __restrict__ out) {
  const int w = blockIdx.x;
  const int b = blockIdx.y;
  const int t = threadIdx.x;
  const int nsb = ns[b];
  float* orow = out + ((size_t)b * NW + w) * OUTW;

  if (w >= nsb) {  // padding word positions -> zero vector (1074 = 537 float2)
    float2* o2 = reinterpret_cast<float2*>(orow);
    for (int j = t; j < OUTW / 2; j += 256) o2[j] = make_float2(0.0f, 0.0f);
    return;
  }

  float4 m = make_float4(-INFINITY, -INFINITY, -INFINITY, -INFINITY);
  if (w == nsb - 1) {
    // last word token: reduce the 32 chunk partials (prefix max of context)
    const float* p = partial + (size_t)b * CHUNKS * HH;
    for (int c = 0; c < CHUNKS; ++c) {
      const float4 v = *reinterpret_cast<const float4*>(p + (size_t)c * HH + 4 * t);
      m.x = fmaxf(m.x, v.x);
      m.y = fmaxf(m.y, v.y);
      m.z = fmaxf(m.z, v.z);
      m.w = fmaxf(m.w, v.w);
    }
  } else {
    // segment max over this word's contiguous subword span.
    // start[] has no sentinel: the last real word (w == nsb-2) ends at S.
    const int s0 = start[b * NW + w];
    const int s1 = (w == nsb - 2) ? SS : start[b * NW + w + 1];
    const float* cb = ctx + (size_t)b * SS * HH;
    for (int s = s0; s < s1; ++s) {
      const float4 v = *reinterpret_cast<const float4*>(cb + (size_t)s * HH + 4 * t);
      m.x = fmaxf(m.x, v.x);
      m.y = fmaxf(m.y, v.y);
      m.z = fmaxf(m.z, v.z);
      m.w = fmaxf(m.w, v.w);
    }
  }

  // Store H part. Row stride is 1074 floats -> rows only 8B aligned; use float2.
  float2* o2 = reinterpret_cast<float2*>(orow);
  o2[2 * t]     = make_float2(m.x, m.y);
  o2[2 * t + 1] = make_float2(m.z, m.w);

  // DW tail
  if (t < DWW) {
    float v;
    if (w == nsb - 1) {
      float mm = -INFINITY;
      const float* lp = lastwp + (size_t)b * CHUNKS * 64;
      for (int c = 0; c < CHUNKS; ++c) mm = fmaxf(mm, lp[c * 64 + t]);
      v = mm;
    } else {
      v = wemb[((size_t)b * NW + w) * DWW + t];
    }
    orow[HH + t] = v;
  }
}

extern "C" void kernel_launch(void* const* d_in, const int* in_sizes, int n_in,
                              void* d_out, int out_size, void* d_ws, size_t ws_size,
                              hipStream_t stream) {
  const float* ctx  = (const float*)d_in[0];  // [B,S,H]
  const float* wemb = (const float*)d_in[1];  // [B,N,DW]
  const int*   seg  = (const int*)d_in[2];    // [B,S]
  const int*   ns   = (const int*)d_in[3];    // [B]
  float* out = (float*)d_out;

  char* ws = (char*)d_ws;
  int*   start   = (int*)(ws + WS_START_OFF);
  float* partial = (float*)(ws + WS_PARTIAL_OFF);
  float* lastwp  = (float*)(ws + WS_LASTWP_OFF);

  k_pre<<<dim3(CHUNKS, BB), dim3(256), 0, stream>>>(ctx, wemb, seg, ns, start, partial, lastwp);
  k_main<<<dim3(NW, BB), dim3(256), 0, stream>>>(ctx, wemb, ns, start, partial, lastwp, out);
}